// Round 3
// baseline (94.022 us; speedup 1.0000x reference)
//
#include <hip/hip_runtime.h>

// RASP pairwise score, N=6144, P = N(N-1)/2 pairs.
// R3: pot tensor slice per tile staged in LDS (type-sorted atoms => a 128-atom
// tile spans ~2 types; slice = 6*nti*ntj*21 floats ~ 4.5 KB). Inner loop has
// ZERO global memory ops: ds_read_b128 (jtile) + ds_read2_b32 (e0,e1) + ~27 VALU.
// Invalid (type -1) atoms get poisoned coords (dist >> 20) so no validity
// checks needed in the hot loop.

#define T_TYPES 85
#define D_BINS 21
#define TSTRIDE (T_TYPES * D_BINS)            // 1785
#define KSTRIDE (T_TYPES * T_TYPES * D_BINS)  // 151725
#define INVALID_KEY 85
#define NKEYS 86
#define TILE 128
#define PTHREADS 512
#define JCHUNK (TILE / (PTHREADS / TILE))     // 32
#define MAXSLOTS 36

// Single-block counting sort + invalid-coord poisoning + output zeroing.
__global__ __launch_bounds__(1024) void sort_kernel(const float* __restrict__ coords,
                                                    const int* __restrict__ res_ids,
                                                    const int* __restrict__ types, int n,
                                                    float4* __restrict__ sorted,
                                                    float* __restrict__ out) {
    __shared__ int hist[NKEYS];
    __shared__ int offs[NKEYS];
    int tid = threadIdx.x;
    if (tid < NKEYS) hist[tid] = 0;
    if (tid == 0) *out = 0.0f;
    __syncthreads();
    for (int i = tid; i < n; i += 1024) {
        int t = types[i];
        atomicAdd(&hist[(t < 0) ? INVALID_KEY : t], 1);
    }
    __syncthreads();
    if (tid == 0) {
        int s = 0;
        for (int i = 0; i < NKEYS; ++i) { offs[i] = s; s += hist[i]; }
    }
    __syncthreads();
    for (int i = tid; i < n; i += 1024) {
        int t = types[i];
        int key = (t < 0) ? INVALID_KEY : t;
        int pos = atomicAdd(&offs[key], 1);
        float4 v;
        if (t < 0) {
            // poison: any pair involving this atom has dist >= 1000 >> 20,
            // and distinct invalid atoms are >= 1000 apart from each other.
            v.x = 1.0e6f + 1000.0f * (float)pos;
            v.y = 0.0f; v.z = 0.0f;
            v.w = __int_as_float((res_ids[i] << 7) | 84);  // label clamped; masked anyway
        } else {
            v.x = coords[3 * i + 0];
            v.y = coords[3 * i + 1];
            v.z = coords[3 * i + 2];
            v.w = __int_as_float((res_ids[i] << 7) | t);
        }
        sorted[pos] = v;
    }
}

__global__ __launch_bounds__(PTHREADS) void pair_kernel(const float4* __restrict__ sorted,
                                                        const float* __restrict__ pot,
                                                        int n, int nt,
                                                        float* __restrict__ out) {
    __shared__ float4 jtile[TILE];
    __shared__ float pot_s[6 * MAXSLOTS * D_BINS];   // [k][slot][d], 18.1 KB
    __shared__ float wsum[PTHREADS / 64];

    int b = blockIdx.x;
    // decode triangular (bi, bj), bi <= bj; row_start(r) = r*nt - r*(r-1)/2
    int bi = (int)((2.0 * nt + 1.0 -
                    sqrt((2.0 * nt + 1.0) * (2.0 * nt + 1.0) - 8.0 * (double)b)) * 0.5);
    if (bi < 0) bi = 0;
    if (bi > nt - 1) bi = nt - 1;
    while ((bi + 1) * nt - ((bi + 1) * bi) / 2 <= b) ++bi;
    while (bi * nt - (bi * (bi - 1)) / 2 > b) --bi;
    int bj = bi + (b - (bi * nt - (bi * (bi - 1)) / 2));

    int tid = threadIdx.x;
    int ilane = tid & (TILE - 1);
    int chunk = tid >> 7;
    int i0 = bi * TILE, q0 = bj * TILE;

    // tile type ranges (wave-uniform; sorted => contiguous types)
    int ihi = min(i0 + TILE, n) - 1;
    int jhi = min(q0 + TILE, n) - 1;
    int tloi = min(__float_as_int(sorted[i0].w) & 127, 84);
    int thii = min(__float_as_int(sorted[ihi].w) & 127, 84);
    int tloj = min(__float_as_int(sorted[q0].w) & 127, 84);
    int thij = min(__float_as_int(sorted[jhi].w) & 127, 84);
    int nti = thii - tloi + 1;
    int ntj = thij - tloj + 1;
    int slots = nti * ntj;
    bool staged = (slots <= MAXSLOTS);

    if (tid < TILE) {
        int q = q0 + tid;
        float4 v;
        if (q < n) v = sorted[q];
        else { v.x = 3.0e7f; v.y = 0.f; v.z = 0.f; v.w = __int_as_float(0); }
        jtile[tid] = v;
    }

    if (staged) {
        int total = 6 * slots * D_BINS;
        for (int e = tid; e < total; e += PTHREADS) {
            int d = e % D_BINS;
            int s2 = e / D_BINS;
            int slot = s2 % slots;
            int k = s2 / slots;
            int tii = slot / ntj;
            int tjj = slot - tii * ntj;
            pot_s[e] = pot[k * KSTRIDE + (tloi + tii) * TSTRIDE + (tloj + tjj) * D_BINS + d];
        }
    }
    __syncthreads();

    int p = i0 + ilane;
    float4 mine;
    if (p < n) mine = sorted[p];
    else { mine.x = 2.0e7f; mine.y = 0.f; mine.z = 0.f; mine.w = __int_as_float(0); }

    int pki = __float_as_int(mine.w);
    int keyi = pki & 127;
    int resi = pki >> 7;
    int islot = min(max(keyi - tloi, 0), nti - 1);
    int sbase = islot * ntj;
    int tibase_g = min(keyi, 84) * TSTRIDE;
    int pjb = p - q0;            // valid requires jj > pjb (handles diag + off-diag)

    float acc = 0.0f;
    int j0 = chunk * JCHUNK;

    if (staged) {
#pragma unroll 8
        for (int u = 0; u < JCHUNK; ++u) {
            int jj = j0 + u;
            float4 o = jtile[jj];
            float dx = mine.x - o.x;
            float dy = mine.y - o.y;
            float dz = mine.z - o.z;
            float d2 = dx * dx + dy * dy + dz * dz;
            float dist = __builtin_amdgcn_sqrtf(d2);

            int pkj = __float_as_int(o.w);
            int keyj = pkj & 127;
            int resj = pkj >> 7;
            int sep = abs(resi - resj);
            int jslot = min(max(keyj - tloj, 0), ntj - 1);
            int k = min(max(sep - 1, 0), 5);
            int d0i = min((int)dist, 19);
            float alpha = dist - (float)d0i;

            int li = (k * slots + sbase + jslot) * D_BINS + d0i;
            float e0 = pot_s[li];
            float e1 = pot_s[li + 1];
            float val = __builtin_fmaf(alpha, e1 - e0, e0) - 2.7f;
            bool valid = (sep > 2) && (dist < 20.0f) && (jj > pjb);
            acc += valid ? val : 0.0f;
        }
    } else {
        // rare fallback: tile spans too many types -> gather from global pot
#pragma unroll 4
        for (int u = 0; u < JCHUNK; ++u) {
            int jj = j0 + u;
            float4 o = jtile[jj];
            float dx = mine.x - o.x;
            float dy = mine.y - o.y;
            float dz = mine.z - o.z;
            float d2 = dx * dx + dy * dy + dz * dz;
            float dist = __builtin_amdgcn_sqrtf(d2);

            int pkj = __float_as_int(o.w);
            int keyj = min(pkj & 127, 84);
            int resj = pkj >> 7;
            int sep = abs(resi - resj);
            int k = min(max(sep - 1, 0), 5);
            int d0i = min((int)dist, 19);
            float alpha = dist - (float)d0i;

            int gi = k * KSTRIDE + tibase_g + keyj * D_BINS + d0i;
            float e0 = pot[gi];
            float e1 = pot[gi + 1];
            float val = __builtin_fmaf(alpha, e1 - e0, e0) - 2.7f;
            bool valid = (sep > 2) && (dist < 20.0f) && (jj > pjb);
            acc += valid ? val : 0.0f;
        }
    }

    // wave reduce -> block reduce -> one atomic
#pragma unroll
    for (int off = 32; off > 0; off >>= 1)
        acc += __shfl_down(acc, off, 64);
    int wave = tid >> 6;
    int lane = tid & 63;
    if (lane == 0) wsum[wave] = acc;
    __syncthreads();
    if (tid == 0) {
        float s = 0.f;
#pragma unroll
        for (int w = 0; w < PTHREADS / 64; ++w) s += wsum[w];
        atomicAdd(out, s);
    }
}

extern "C" void kernel_launch(void* const* d_in, const int* in_sizes, int n_in,
                              void* d_out, int out_size, void* d_ws, size_t ws_size,
                              hipStream_t stream) {
    const float* coords = (const float*)d_in[0];
    const int* res_ids = (const int*)d_in[1];
    const int* types   = (const int*)d_in[2];
    const float* pot   = (const float*)d_in[3];
    int n = in_sizes[1];
    float* out = (float*)d_out;

    float4* sorted = (float4*)d_ws;

    sort_kernel<<<1, 1024, 0, stream>>>(coords, res_ids, types, n, sorted, out);

    int nt = (n + TILE - 1) / TILE;
    int nblocks = nt * (nt + 1) / 2;
    pair_kernel<<<nblocks, PTHREADS, 0, stream>>>(sorted, pot, n, nt, out);
}